// Round 1
// baseline (1339.025 us; speedup 1.0000x reference)
//
#include <hip/hip_runtime.h>

#define DEV_INLINE __device__ __forceinline__

constexpr float BN_EPS = 1e-5f;

DEV_INLINE ushort f2bf(float f) {
  unsigned int u = __float_as_uint(f);
  unsigned int r = (u + 0x7FFFu + ((u >> 16) & 1u)) >> 16;
  return (ushort)r;
}
DEV_INLINE float bf2f(ushort b) { return __uint_as_float(((unsigned int)b) << 16); }

DEV_INLINE void fma16(float (&acc)[4][4], const float4 a4, const float4 b4) {
  const float aa[4] = {a4.x, a4.y, a4.z, a4.w};
  const float bb[4] = {b4.x, b4.y, b4.z, b4.w};
#pragma unroll
  for (int i = 0; i < 4; ++i)
#pragma unroll
    for (int j = 0; j < 4; ++j) acc[i][j] = fmaf(aa[i], bb[j], acc[i][j]);
}

// -------------------- zero stats region --------------------
__global__ void kZero(float* p, int n) {
  int i = blockIdx.x * blockDim.x + threadIdx.x;
  if (i < n) p[i] = 0.f;
}

// -------------------- reduce X -> sx(64), G=X^T X (64x64) --------------------
__global__ __launch_bounds__(256) void kReduceX(const float* __restrict__ X,
                                                float* __restrict__ sx,
                                                float* __restrict__ G, int N) {
  __shared__ float Hs[64][68];
  const int tid = threadIdx.x;
  const int ti = tid >> 4, tj = tid & 15;
  const int c4 = tid & 15, r0 = tid >> 4;
  float acc[4][4] = {};
  float sacc[4] = {0.f, 0.f, 0.f, 0.f};
  for (int chunk = 0; chunk < 2; ++chunk) {
    const int base = blockIdx.x * 128 + chunk * 64;
    __syncthreads();
#pragma unroll
    for (int q = 0; q < 4; ++q) {
      const int rr = r0 + q * 16;
      const int grow = base + rr;
      float4 v = make_float4(0.f, 0.f, 0.f, 0.f);
      if (grow < N) v = *reinterpret_cast<const float4*>(&X[(size_t)grow * 64 + c4 * 4]);
      *reinterpret_cast<float4*>(&Hs[rr][c4 * 4]) = v;
    }
    __syncthreads();
#pragma unroll 4
    for (int r = 0; r < 64; ++r) {
      const float4 a4 = *reinterpret_cast<const float4*>(&Hs[r][ti * 4]);
      const float4 b4 = *reinterpret_cast<const float4*>(&Hs[r][tj * 4]);
      fma16(acc, a4, b4);
      if (ti == 0) { sacc[0] += b4.x; sacc[1] += b4.y; sacc[2] += b4.z; sacc[3] += b4.w; }
    }
  }
#pragma unroll
  for (int i = 0; i < 4; ++i)
#pragma unroll
    for (int j = 0; j < 4; ++j)
      atomicAdd(&G[(ti * 4 + i) * 64 + (tj * 4 + j)], acc[i][j]);
  if (ti == 0) {
#pragma unroll
    for (int j = 0; j < 4; ++j) atomicAdd(&sx[tj * 4 + j], sacc[j]);
  }
}

// -------------------- BN stats via Gram: Y = A@W, A has Gram G, colsum s ----
__global__ __launch_bounds__(64) void kBnStatsGram(
    const float* __restrict__ W, int ldw, const float* __restrict__ g,
    const float* __restrict__ b, const float* __restrict__ G,
    const float* __restrict__ s, float invN, float* __restrict__ a_out,
    float* __restrict__ c_out) {
  const int j = blockIdx.x;
  const int p = threadIdx.x;  // 0..63
  const float wp = W[(size_t)p * ldw + j];
  float t = 0.f;
#pragma unroll 8
  for (int r = 0; r < 64; ++r) t = fmaf(G[p * 64 + r], W[(size_t)r * ldw + j], t);
  float q = wp * t;
  float mp = s[p] * wp;
#pragma unroll
  for (int off = 32; off > 0; off >>= 1) {
    q += __shfl_down(q, off);
    mp += __shfl_down(mp, off);
  }
  if (p == 0) {
    const float m = mp * invN;
    const float v = fmaxf(q * invN - m * m, 0.f);
    const float a = g[j] * rsqrtf(v + BN_EPS);
    a_out[j] = a;
    c_out[j] = fmaf(-m, a, b[j]);
  }
}

// -------------------- finalize BN2 stats from atomic col sums --------------
__global__ __launch_bounds__(64) void kStats2(const float* __restrict__ colsum,
                                              const float* __restrict__ colsq,
                                              const float* __restrict__ g,
                                              const float* __restrict__ b, float invN,
                                              float* __restrict__ a_out,
                                              float* __restrict__ c_out) {
  const int j = threadIdx.x;
  const float m = colsum[j] * invN;
  const float v = fmaxf(colsq[j] * invN - m * m, 0.f);
  const float a = g[j] * rsqrtf(v + BN_EPS);
  a_out[j] = a;
  c_out[j] = fmaf(-m, a, b[j]);
}

// -------------------- h1 = relu(a*(X@W1)+c), N x 64 -------------------------
__global__ __launch_bounds__(256) void kAffineGemm64(
    const float* __restrict__ A, const float* __restrict__ W,
    const float* __restrict__ av, const float* __restrict__ cv,
    float* __restrict__ O, int N) {
  __shared__ float As[64][64];  // transposed: [k][row]
  __shared__ float Bs[64][64];  // [k][col]
  const int tid = threadIdx.x;
  const int ti = tid >> 4, tj = tid & 15;
  const int row0 = blockIdx.x * 64;
  const int c4 = tid & 15, r0 = tid >> 4;
#pragma unroll
  for (int q = 0; q < 4; ++q) {
    const int kk = r0 + q * 16;
    *reinterpret_cast<float4*>(&Bs[kk][c4 * 4]) =
        *reinterpret_cast<const float4*>(&W[(size_t)kk * 64 + c4 * 4]);
    const int grow = row0 + kk;
    float4 v = make_float4(0.f, 0.f, 0.f, 0.f);
    if (grow < N) v = *reinterpret_cast<const float4*>(&A[(size_t)grow * 64 + c4 * 4]);
    As[c4 * 4 + 0][kk] = v.x;
    As[c4 * 4 + 1][kk] = v.y;
    As[c4 * 4 + 2][kk] = v.z;
    As[c4 * 4 + 3][kk] = v.w;
  }
  __syncthreads();
  float acc[4][4] = {};
#pragma unroll 4
  for (int k = 0; k < 64; ++k) {
    const float4 a4 = *reinterpret_cast<const float4*>(&As[k][ti * 4]);
    const float4 b4 = *reinterpret_cast<const float4*>(&Bs[k][tj * 4]);
    fma16(acc, a4, b4);
  }
  float aj[4], cj[4];
#pragma unroll
  for (int j = 0; j < 4; ++j) { aj[j] = av[tj * 4 + j]; cj[j] = cv[tj * 4 + j]; }
#pragma unroll
  for (int i = 0; i < 4; ++i) {
    const int r = row0 + ti * 4 + i;
    if (r < N) {
      float4 o;
      o.x = fmaxf(fmaf(acc[i][0], aj[0], cj[0]), 0.f);
      o.y = fmaxf(fmaf(acc[i][1], aj[1], cj[1]), 0.f);
      o.z = fmaxf(fmaf(acc[i][2], aj[2], cj[2]), 0.f);
      o.w = fmaxf(fmaf(acc[i][3], aj[3], cj[3]), 0.f);
      *reinterpret_cast<float4*>(&O[(size_t)r * 64 + tj * 4]) = o;
    }
  }
}

// -------------------- conv: Y2 = sum_k gather_k(h1) @ Wk[k], + col stats ----
__global__ __launch_bounds__(256) void kConv(
    const float* __restrict__ H1, const int* __restrict__ nbr,
    const float* __restrict__ Wk, float* __restrict__ Y2,
    float* __restrict__ colsum, float* __restrict__ colsq, int N) {
  __shared__ float As[64][64];  // gathered, transposed [k][row]
  __shared__ float Bs[64][64];  // Wk[k] [k][col]
  __shared__ int idxs[64];
  __shared__ float redsum[64];
  __shared__ float redsq[64];
  const int tid = threadIdx.x;
  const int ti = tid >> 4, tj = tid & 15;
  const int row0 = blockIdx.x * 64;
  const int c4 = tid & 15, r0 = tid >> 4;
  float acc[4][4] = {};
  for (int k = 0; k < 9; ++k) {
    __syncthreads();
    if (tid < 64) {
      const int r = row0 + tid;
      idxs[tid] = (r < N) ? nbr[(size_t)r * 9 + k] : -1;
    }
#pragma unroll
    for (int q = 0; q < 4; ++q) {
      const int kk = r0 + q * 16;
      *reinterpret_cast<float4*>(&Bs[kk][c4 * 4]) =
          *reinterpret_cast<const float4*>(&Wk[(size_t)k * 4096 + (size_t)kk * 64 + c4 * 4]);
    }
    __syncthreads();
#pragma unroll
    for (int q = 0; q < 4; ++q) {
      const int rr = r0 + q * 16;
      const int src = idxs[rr];
      float4 v = make_float4(0.f, 0.f, 0.f, 0.f);
      if (src >= 0) v = *reinterpret_cast<const float4*>(&H1[(size_t)src * 64 + c4 * 4]);
      As[c4 * 4 + 0][rr] = v.x;
      As[c4 * 4 + 1][rr] = v.y;
      As[c4 * 4 + 2][rr] = v.z;
      As[c4 * 4 + 3][rr] = v.w;
    }
    __syncthreads();
#pragma unroll 4
    for (int kk = 0; kk < 64; ++kk) {
      const float4 a4 = *reinterpret_cast<const float4*>(&As[kk][ti * 4]);
      const float4 b4 = *reinterpret_cast<const float4*>(&Bs[kk][tj * 4]);
      fma16(acc, a4, b4);
    }
  }
  // epilogue: write Y2 + column sum / sumsq for BN2
  if (tid < 64) { redsum[tid] = 0.f; redsq[tid] = 0.f; }
  __syncthreads();
#pragma unroll
  for (int i = 0; i < 4; ++i) {
    const int r = row0 + ti * 4 + i;
    if (r < N) {
      float4 o = make_float4(acc[i][0], acc[i][1], acc[i][2], acc[i][3]);
      *reinterpret_cast<float4*>(&Y2[(size_t)r * 64 + tj * 4]) = o;
#pragma unroll
      for (int j = 0; j < 4; ++j) {
        atomicAdd(&redsum[tj * 4 + j], acc[i][j]);
        atomicAdd(&redsq[tj * 4 + j], acc[i][j] * acc[i][j]);
      }
    }
  }
  __syncthreads();
  if (tid < 64) {
    atomicAdd(&colsum[tid], redsum[tid]);
    atomicAdd(&colsq[tid], redsq[tid]);
  }
}

// ---- h2 = relu(a2*Y2+c2) (stored bf16) + Gram(h2), colsum(h2) --------------
__global__ __launch_bounds__(256) void kH2Gram(
    const float* __restrict__ Y2, const float* __restrict__ av,
    const float* __restrict__ cv, ushort* __restrict__ H2,
    float* __restrict__ sh, float* __restrict__ Gh, int N) {
  __shared__ float Hs[64][68];
  const int tid = threadIdx.x;
  const int ti = tid >> 4, tj = tid & 15;
  const int c4 = tid & 15, r0 = tid >> 4;
  float aj[4], cj[4];
#pragma unroll
  for (int j = 0; j < 4; ++j) { aj[j] = av[c4 * 4 + j]; cj[j] = cv[c4 * 4 + j]; }
  float acc[4][4] = {};
  float sacc[4] = {0.f, 0.f, 0.f, 0.f};
  for (int chunk = 0; chunk < 2; ++chunk) {
    const int base = blockIdx.x * 128 + chunk * 64;
    __syncthreads();
#pragma unroll
    for (int q = 0; q < 4; ++q) {
      const int rr = r0 + q * 16;
      const int grow = base + rr;
      float4 h = make_float4(0.f, 0.f, 0.f, 0.f);
      if (grow < N) {
        const float4 y = *reinterpret_cast<const float4*>(&Y2[(size_t)grow * 64 + c4 * 4]);
        h.x = fmaxf(fmaf(y.x, aj[0], cj[0]), 0.f);
        h.y = fmaxf(fmaf(y.y, aj[1], cj[1]), 0.f);
        h.z = fmaxf(fmaf(y.z, aj[2], cj[2]), 0.f);
        h.w = fmaxf(fmaf(y.w, aj[3], cj[3]), 0.f);
        ushort4 u;
        u.x = f2bf(h.x); u.y = f2bf(h.y); u.z = f2bf(h.z); u.w = f2bf(h.w);
        *reinterpret_cast<ushort4*>(&H2[(size_t)grow * 64 + c4 * 4]) = u;
      }
      *reinterpret_cast<float4*>(&Hs[rr][c4 * 4]) = h;
    }
    __syncthreads();
#pragma unroll 4
    for (int r = 0; r < 64; ++r) {
      const float4 a4 = *reinterpret_cast<const float4*>(&Hs[r][ti * 4]);
      const float4 b4 = *reinterpret_cast<const float4*>(&Hs[r][tj * 4]);
      fma16(acc, a4, b4);
      if (ti == 0) { sacc[0] += b4.x; sacc[1] += b4.y; sacc[2] += b4.z; sacc[3] += b4.w; }
    }
  }
#pragma unroll
  for (int i = 0; i < 4; ++i)
#pragma unroll
    for (int j = 0; j < 4; ++j)
      atomicAdd(&Gh[(ti * 4 + i) * 64 + (tj * 4 + j)], acc[i][j]);
  if (ti == 0) {
#pragma unroll
    for (int j = 0; j < 4; ++j) atomicAdd(&sh[tj * 4 + j], sacc[j]);
  }
}

// ---- out = relu(a3*(h2@W3)+c3 + as*(X@Ws)+cs), N x 256 ---------------------
__global__ __launch_bounds__(256) void kFinal(
    const ushort* __restrict__ H2, const float* __restrict__ X,
    const float* __restrict__ W3, const float* __restrict__ Ws,
    const float* __restrict__ a3, const float* __restrict__ c3,
    const float* __restrict__ as_, const float* __restrict__ cs_,
    float* __restrict__ OUT, int N) {
  __shared__ float A1[64][64];  // h2 transposed [k][row]
  __shared__ float A2[64][64];  // X  transposed [k][row]
  __shared__ float B1[64][64];  // W3 slice [k][col]
  __shared__ float B2[64][64];  // Ws slice [k][col]
  const int tid = threadIdx.x;
  const int ti = tid >> 4, tj = tid & 15;
  const int row0 = blockIdx.x * 64;
  const int col0 = blockIdx.y * 64;
  const int c4 = tid & 15, r0 = tid >> 4;
#pragma unroll
  for (int q = 0; q < 4; ++q) {
    const int kk = r0 + q * 16;
    *reinterpret_cast<float4*>(&B1[kk][c4 * 4]) =
        *reinterpret_cast<const float4*>(&W3[(size_t)kk * 256 + col0 + c4 * 4]);
    *reinterpret_cast<float4*>(&B2[kk][c4 * 4]) =
        *reinterpret_cast<const float4*>(&Ws[(size_t)kk * 256 + col0 + c4 * 4]);
    const int grow = row0 + kk;
    float4 v1 = make_float4(0.f, 0.f, 0.f, 0.f);
    float4 v2 = make_float4(0.f, 0.f, 0.f, 0.f);
    if (grow < N) {
      const ushort4 u = *reinterpret_cast<const ushort4*>(&H2[(size_t)grow * 64 + c4 * 4]);
      v1.x = bf2f(u.x); v1.y = bf2f(u.y); v1.z = bf2f(u.z); v1.w = bf2f(u.w);
      v2 = *reinterpret_cast<const float4*>(&X[(size_t)grow * 64 + c4 * 4]);
    }
    A1[c4 * 4 + 0][kk] = v1.x; A1[c4 * 4 + 1][kk] = v1.y;
    A1[c4 * 4 + 2][kk] = v1.z; A1[c4 * 4 + 3][kk] = v1.w;
    A2[c4 * 4 + 0][kk] = v2.x; A2[c4 * 4 + 1][kk] = v2.y;
    A2[c4 * 4 + 2][kk] = v2.z; A2[c4 * 4 + 3][kk] = v2.w;
  }
  __syncthreads();
  float acc1[4][4] = {};
  float acc2[4][4] = {};
#pragma unroll 2
  for (int k = 0; k < 64; ++k) {
    const float4 a14 = *reinterpret_cast<const float4*>(&A1[k][ti * 4]);
    const float4 b14 = *reinterpret_cast<const float4*>(&B1[k][tj * 4]);
    fma16(acc1, a14, b14);
    const float4 a24 = *reinterpret_cast<const float4*>(&A2[k][ti * 4]);
    const float4 b24 = *reinterpret_cast<const float4*>(&B2[k][tj * 4]);
    fma16(acc2, a24, b24);
  }
  float a3j[4], c3j[4], asj[4], csj[4];
#pragma unroll
  for (int j = 0; j < 4; ++j) {
    a3j[j] = a3[col0 + tj * 4 + j];
    c3j[j] = c3[col0 + tj * 4 + j];
    asj[j] = as_[col0 + tj * 4 + j];
    csj[j] = cs_[col0 + tj * 4 + j];
  }
#pragma unroll
  for (int i = 0; i < 4; ++i) {
    const int r = row0 + ti * 4 + i;
    if (r < N) {
      float4 o;
      o.x = fmaxf(fmaf(acc1[i][0], a3j[0], c3j[0]) + fmaf(acc2[i][0], asj[0], csj[0]), 0.f);
      o.y = fmaxf(fmaf(acc1[i][1], a3j[1], c3j[1]) + fmaf(acc2[i][1], asj[1], csj[1]), 0.f);
      o.z = fmaxf(fmaf(acc1[i][2], a3j[2], c3j[2]) + fmaf(acc2[i][2], asj[2], csj[2]), 0.f);
      o.w = fmaxf(fmaf(acc1[i][3], a3j[3], c3j[3]) + fmaf(acc2[i][3], asj[3], csj[3]), 0.f);
      *reinterpret_cast<float4*>(&OUT[(size_t)r * 256 + col0 + tj * 4]) = o;
    }
  }
}

extern "C" void kernel_launch(void* const* d_in, const int* in_sizes, int n_in,
                              void* d_out, int out_size, void* d_ws, size_t ws_size,
                              hipStream_t stream) {
  const float* X  = (const float*)d_in[0];
  const int*   nbr = (const int*)d_in[1];
  const float* W1 = (const float*)d_in[2];
  const float* g1 = (const float*)d_in[3];
  const float* b1 = (const float*)d_in[4];
  const float* Wk = (const float*)d_in[5];
  const float* g2 = (const float*)d_in[6];
  const float* b2 = (const float*)d_in[7];
  const float* W3 = (const float*)d_in[8];
  const float* g3 = (const float*)d_in[9];
  const float* b3 = (const float*)d_in[10];
  const float* Ws = (const float*)d_in[11];
  const float* gs = (const float*)d_in[12];
  const float* bs = (const float*)d_in[13];
  float* out = (float*)d_out;
  float* ws  = (float*)d_ws;

  const int N = in_sizes[0] / 64;
  const float invN = 1.f / (float)N;

  // ws layout (floats)
  float* sx      = ws + 0;
  float* G       = ws + 64;
  float* convsum = ws + 4160;
  float* convsq  = ws + 4224;
  float* sh2     = ws + 4288;
  float* Gh2     = ws + 4352;
  float* a1 = ws + 8448, *c1 = ws + 8512;
  float* as_ = ws + 8576, *cs_ = ws + 8832;
  float* a2 = ws + 9088, *c2 = ws + 9152;
  float* a3 = ws + 9216, *c3 = ws + 9472;
  ushort* h2 = (ushort*)(ws + 10240);          // N*64 bf16 (~33 MB)
  // scratch staged in d_out (dead before kFinal writes)
  float* h1 = out;                             // N*64 f32
  float* Y2 = out + (size_t)N * 64;            // N*64 f32

  const int gb64  = (N + 63) / 64;
  const int gb128 = (N + 127) / 128;

  kZero<<<38, 256, 0, stream>>>(ws, 9728);
  kReduceX<<<gb128, 256, 0, stream>>>(X, sx, G, N);
  kBnStatsGram<<<64, 64, 0, stream>>>(W1, 64, g1, b1, G, sx, invN, a1, c1);
  kBnStatsGram<<<256, 64, 0, stream>>>(Ws, 256, gs, bs, G, sx, invN, as_, cs_);
  kAffineGemm64<<<gb64, 256, 0, stream>>>(X, W1, a1, c1, h1, N);
  kConv<<<gb64, 256, 0, stream>>>(h1, nbr, Wk, Y2, convsum, convsq, N);
  kStats2<<<1, 64, 0, stream>>>(convsum, convsq, g2, b2, invN, a2, c2);
  kH2Gram<<<gb128, 256, 0, stream>>>(Y2, a2, c2, h2, sh2, Gh2, N);
  kBnStatsGram<<<256, 64, 0, stream>>>(W3, 256, g3, b3, Gh2, sh2, invN, a3, c3);
  kFinal<<<dim3(gb64, 4), 256, 0, stream>>>(h2, X, W3, Ws, a3, c3, as_, cs_, out, N);
}

// Round 2
// 502.895 us; speedup vs baseline: 2.6626x; 2.6626x over previous
//
#include <hip/hip_runtime.h>

typedef __attribute__((ext_vector_type(8))) short  s16x8;
typedef __attribute__((ext_vector_type(8))) unsigned short u16x8;
typedef __attribute__((ext_vector_type(4))) float  f32x4;

constexpr float BN_EPS = 1e-5f;
#define DEV_INLINE __device__ __forceinline__

DEV_INLINE ushort f2bf(float f) {
  unsigned int u = __float_as_uint(f);
  return (ushort)((u + 0x7FFFu + ((u >> 16) & 1u)) >> 16);
}

DEV_INLINE f32x4 mfma16(s16x8 a, s16x8 b, f32x4 c) {
  return __builtin_amdgcn_mfma_f32_16x16x32_bf16(a, b, c, 0, 0, 0);
}

// packed B-fragment index decode: r in [0,1024) -> (k, col16)
DEV_INLINE void decode_frag(int r, int& k, int& c16) {
  const int ks = r >> 9;
  const int l = (r >> 3) & 63;
  const int j = r & 7;
  k = ks * 32 + ((l >> 4) << 3) + j;
  c16 = l & 15;
}

__global__ void kZero(float* p, int n) {
  int i = blockIdx.x * blockDim.x + threadIdx.x;
  if (i < n) p[i] = 0.f;
}

// ---- pack W1|Ws (20 ct), Wk (9 taps x 4 ct), W3 (16 ct) into B-fragment order
__global__ void kPackW(const float* __restrict__ W1, const float* __restrict__ Ws,
                       const float* __restrict__ Wk, const float* __restrict__ W3,
                       ushort* __restrict__ WP1S, ushort* __restrict__ WPk,
                       ushort* __restrict__ WP3) {
  int e = blockIdx.x * 256 + threadIdx.x;  // 73728 total
  if (e < 20480) {
    int ct = e >> 10, r = e & 1023, k, c16;
    decode_frag(r, k, c16);
    float w = (ct < 4) ? W1[k * 64 + ct * 16 + c16] : Ws[k * 256 + (ct - 4) * 16 + c16];
    WP1S[e] = f2bf(w);
  } else if (e < 57344) {
    int e2 = e - 20480;
    int tap = e2 >> 12, r2 = e2 & 4095;
    int ct = r2 >> 10, k, c16;
    decode_frag(r2 & 1023, k, c16);
    WPk[e2] = f2bf(Wk[tap * 4096 + k * 64 + ct * 16 + c16]);
  } else {
    int e3 = e - 57344;
    int ct = e3 >> 10, k, c16;
    decode_frag(e3 & 1023, k, c16);
    WP3[e3] = f2bf(W3[k * 256 + ct * 16 + c16]);
  }
}

// ---- finalize BN affine params from col sums -------------------------------
__global__ void kFinStats(const float* __restrict__ sum, const float* __restrict__ sq,
                          const float* __restrict__ g, const float* __restrict__ b,
                          float invN, float* __restrict__ a, float* __restrict__ c, int n) {
  int j = blockIdx.x * blockDim.x + threadIdx.x;
  if (j < n) {
    float m = sum[j] * invN;
    float v = fmaxf(sq[j] * invN - m * m, 0.f);
    float al = g[j] * rsqrtf(v + BN_EPS);
    a[j] = al;
    c[j] = fmaf(-m, al, b[j]);
  }
}

// ---- pack scaled W3*diag(a3), Ws*diag(aS); cc = c3+cS ----------------------
__global__ void kPackScaled(const float* __restrict__ W3, const float* __restrict__ Ws,
                            const float* __restrict__ a3v, const float* __restrict__ aSv,
                            const float* __restrict__ c3v, const float* __restrict__ cSv,
                            ushort* __restrict__ WP3s, ushort* __restrict__ WPSs,
                            float* __restrict__ cc) {
  int e = blockIdx.x * 256 + threadIdx.x;  // 16384
  int ct = e >> 10, k, c16;
  decode_frag(e & 1023, k, c16);
  int col = ct * 16 + c16;
  WP3s[e] = f2bf(W3[k * 256 + col] * a3v[col]);
  WPSs[e] = f2bf(Ws[k * 256 + col] * aSv[col]);
  if (e < 256) cc[e] = c3v[e] + cSv[e];
}

// ---- stage one 64-row f32 tile into swizzled bf16 LDS ----------------------
// thread t handles row r=t>>2, cols [q*16, q*16+16)
DEV_INLINE void stageF32(ushort* At, const float* __restrict__ src, int row0, int N,
                         int tid, float scale_dummy) {
  const int r = tid >> 2, q = tid & 3;
  const int grow = row0 + r;
  u16x8 lo = {0, 0, 0, 0, 0, 0, 0, 0}, hi = {0, 0, 0, 0, 0, 0, 0, 0};
  if (grow < N) {
    const float4* xp = reinterpret_cast<const float4*>(&src[(size_t)grow * 64 + q * 16]);
#pragma unroll
    for (int i = 0; i < 2; ++i) {
      float4 t = xp[i];
      lo[4 * i + 0] = f2bf(t.x); lo[4 * i + 1] = f2bf(t.y);
      lo[4 * i + 2] = f2bf(t.z); lo[4 * i + 3] = f2bf(t.w);
      float4 u = xp[i + 2];
      hi[4 * i + 0] = f2bf(u.x); hi[4 * i + 1] = f2bf(u.y);
      hi[4 * i + 2] = f2bf(u.z); hi[4 * i + 3] = f2bf(u.w);
    }
  }
  char* base = (char*)At + r * 128;
  const int sw = (r & 7) << 4;
  *(u16x8*)(base + ((q * 32) ^ sw)) = lo;
  *(u16x8*)(base + ((q * 32 + 16) ^ sw)) = hi;
}

// ---- K1: colsum/colsq of X@[W1|Ws] (320 cols), no Y store ------------------
__global__ __launch_bounds__(256) void kStatsXW(const float* __restrict__ X,
                                                const ushort* __restrict__ WP,
                                                float* __restrict__ gsum,
                                                float* __restrict__ gsq, int N) {
  __shared__ ushort At[64 * 64];
  __shared__ float lsum[320], lsq[320];
  const int tid = threadIdx.x;
  const int row0 = blockIdx.x * 64;
  for (int i = tid; i < 320; i += 256) { lsum[i] = 0.f; lsq[i] = 0.f; }
  stageF32(At, X, row0, N, tid, 0.f);
  __syncthreads();
  const int l = tid & 63, w = tid >> 6;
  const int rowb = w * 16 + (l & 15);
  const char* abase = (const char*)At + rowb * 128;
  const int sw = (rowb & 7) << 4;
  const int kb = (l >> 4) << 4;
  const s16x8 a0 = *(const s16x8*)(abase + (kb ^ sw));
  const s16x8 a1 = *(const s16x8*)(abase + ((64 + kb) ^ sw));
  const u16x8* wp = (const u16x8*)WP;
#pragma unroll 5
  for (int ct = 0; ct < 20; ++ct) {
    s16x8 b0 = (s16x8)wp[(ct * 2 + 0) * 64 + l];
    s16x8 b1 = (s16x8)wp[(ct * 2 + 1) * 64 + l];
    f32x4 acc = {0.f, 0.f, 0.f, 0.f};
    acc = mfma16(a0, b0, acc);
    acc = mfma16(a1, b1, acc);
    float sp = acc[0] + acc[1] + acc[2] + acc[3];
    float qp = acc[0] * acc[0] + acc[1] * acc[1] + acc[2] * acc[2] + acc[3] * acc[3];
    sp += __shfl_xor(sp, 16); sp += __shfl_xor(sp, 32);
    qp += __shfl_xor(qp, 16); qp += __shfl_xor(qp, 32);
    if ((l >> 4) == 0) {
      atomicAdd(&lsum[ct * 16 + (l & 15)], sp);
      atomicAdd(&lsq[ct * 16 + (l & 15)], qp);
    }
  }
  __syncthreads();
  for (int i = tid; i < 320; i += 256) {
    atomicAdd(&gsum[i], lsum[i]);
    atomicAdd(&gsq[i], lsq[i]);
  }
}

// ---- K2: h1 = relu(a1*(X@W1)+c1) -> bf16 -----------------------------------
__global__ __launch_bounds__(256) void kGemm1(const float* __restrict__ X,
                                              const ushort* __restrict__ WP,
                                              const float* __restrict__ av,
                                              const float* __restrict__ cv,
                                              ushort* __restrict__ H1, int N) {
  __shared__ ushort At[64 * 64];
  const int tid = threadIdx.x;
  const int row0 = blockIdx.x * 64;
  stageF32(At, X, row0, N, tid, 0.f);
  __syncthreads();
  const int l = tid & 63, w = tid >> 6;
  const int rowb = w * 16 + (l & 15);
  const char* abase = (const char*)At + rowb * 128;
  const int sw = (rowb & 7) << 4;
  const int kb = (l >> 4) << 4;
  const s16x8 a0 = *(const s16x8*)(abase + (kb ^ sw));
  const s16x8 a1 = *(const s16x8*)(abase + ((64 + kb) ^ sw));
  const u16x8* wp = (const u16x8*)WP;
#pragma unroll
  for (int ct = 0; ct < 4; ++ct) {
    s16x8 b0 = (s16x8)wp[(ct * 2 + 0) * 64 + l];
    s16x8 b1 = (s16x8)wp[(ct * 2 + 1) * 64 + l];
    f32x4 acc = {0.f, 0.f, 0.f, 0.f};
    acc = mfma16(a0, b0, acc);
    acc = mfma16(a1, b1, acc);
    const int col = ct * 16 + (l & 15);
    const float aj = av[col], cj = cv[col];
#pragma unroll
    for (int reg = 0; reg < 4; ++reg) {
      const int grow = row0 + w * 16 + ((l >> 4) << 2) + reg;
      if (grow < N) H1[(size_t)grow * 64 + col] = f2bf(fmaxf(fmaf(acc[reg], aj, cj), 0.f));
    }
  }
}

// ---- K3: Y2 = sum_k gather_k(h1) @ Wk[k] (MFMA) + BN2 col stats ------------
__global__ __launch_bounds__(256) void kConv(const ushort* __restrict__ H1,
                                             const int* __restrict__ nbr,
                                             const ushort* __restrict__ WPk,
                                             float* __restrict__ Y2,
                                             float* __restrict__ gsum,
                                             float* __restrict__ gsq, int N) {
  __shared__ ushort At[64 * 64];
  __shared__ int idx[576];
  __shared__ float lsum[64], lsq[64];
  const int tid = threadIdx.x;
  const int row0 = blockIdx.x * 64;
  if (tid < 64) { lsum[tid] = 0.f; lsq[tid] = 0.f; }
  for (int e = tid; e < 576; e += 256) {
    const int grow = row0 + e / 9;
    idx[e] = (grow < N) ? nbr[(size_t)row0 * 9 + e] : -1;
  }
  const int l = tid & 63, w = tid >> 6;
  const int rowb = w * 16 + (l & 15);
  const char* abase = (const char*)At + rowb * 128;
  const int swr = (rowb & 7) << 4;
  const int kb = (l >> 4) << 4;
  const int r = tid >> 2, q = tid & 3;
  char* wbase = (char*)At + r * 128;
  const int sww = (r & 7) << 4;
  f32x4 acc[4];
#pragma unroll
  for (int ct = 0; ct < 4; ++ct) acc[ct] = {0.f, 0.f, 0.f, 0.f};
  const u16x8* wp = (const u16x8*)WPk;
  for (int k = 0; k < 9; ++k) {
    __syncthreads();  // idx ready (k=0) / prev reads done
    const int src = idx[r * 9 + k];
    u16x8 lo = {0, 0, 0, 0, 0, 0, 0, 0}, hi = {0, 0, 0, 0, 0, 0, 0, 0};
    if (src >= 0) {
      const u16x8* hp = (const u16x8*)&H1[(size_t)src * 64 + q * 16];
      lo = hp[0];
      hi = hp[1];
    }
    *(u16x8*)(wbase + ((q * 32) ^ sww)) = lo;
    *(u16x8*)(wbase + ((q * 32 + 16) ^ sww)) = hi;
    __syncthreads();
    const s16x8 a0 = *(const s16x8*)(abase + (kb ^ swr));
    const s16x8 a1 = *(const s16x8*)(abase + ((64 + kb) ^ swr));
#pragma unroll
    for (int ct = 0; ct < 4; ++ct) {
      s16x8 b0 = (s16x8)wp[((size_t)((k * 4 + ct) * 2 + 0)) * 64 + l];
      s16x8 b1 = (s16x8)wp[((size_t)((k * 4 + ct) * 2 + 1)) * 64 + l];
      acc[ct] = mfma16(a0, b0, acc[ct]);
      acc[ct] = mfma16(a1, b1, acc[ct]);
    }
  }
#pragma unroll
  for (int ct = 0; ct < 4; ++ct) {
    const f32x4 v = acc[ct];
    const int col = ct * 16 + (l & 15);
#pragma unroll
    for (int reg = 0; reg < 4; ++reg) {
      const int grow = row0 + w * 16 + ((l >> 4) << 2) + reg;
      if (grow < N) Y2[(size_t)grow * 64 + col] = v[reg];
    }
    float sp = v[0] + v[1] + v[2] + v[3];
    float qp = v[0] * v[0] + v[1] * v[1] + v[2] * v[2] + v[3] * v[3];
    sp += __shfl_xor(sp, 16); sp += __shfl_xor(sp, 32);
    qp += __shfl_xor(qp, 16); qp += __shfl_xor(qp, 32);
    if ((l >> 4) == 0) {
      atomicAdd(&lsum[col], sp);
      atomicAdd(&lsq[col], qp);
    }
  }
  __syncthreads();
  if (tid < 64) {
    atomicAdd(&gsum[tid], lsum[tid]);
    atomicAdd(&gsq[tid], lsq[tid]);
  }
}

// ---- K4: h2 = relu(a2*Y2+c2) -> bf16 store + BN3 stats (h2@W3) -------------
__global__ __launch_bounds__(256) void kH2S3(const float* __restrict__ Y2,
                                             const float* __restrict__ a2v,
                                             const float* __restrict__ c2v,
                                             const ushort* __restrict__ WP3,
                                             ushort* __restrict__ H2,
                                             float* __restrict__ gsum,
                                             float* __restrict__ gsq, int N) {
  __shared__ ushort At[64 * 64];
  __shared__ float lsum[256], lsq[256];
  __shared__ float a2s[64], c2s[64];
  const int tid = threadIdx.x;
  const int row0 = blockIdx.x * 64;
  for (int i = tid; i < 256; i += 256) { lsum[i] = 0.f; lsq[i] = 0.f; }
  if (tid < 64) a2s[tid] = a2v[tid];
  else if (tid < 128) c2s[tid - 64] = c2v[tid - 64];
  __syncthreads();
  {
    const int r = tid >> 2, q = tid & 3;
    const int grow = row0 + r;
    u16x8 lo = {0, 0, 0, 0, 0, 0, 0, 0}, hi = {0, 0, 0, 0, 0, 0, 0, 0};
    if (grow < N) {
      const float4* yp = reinterpret_cast<const float4*>(&Y2[(size_t)grow * 64 + q * 16]);
#pragma unroll
      for (int i = 0; i < 2; ++i) {
        float4 t = yp[i];
        float4 u = yp[i + 2];
        const int cb = q * 16;
        lo[4 * i + 0] = f2bf(fmaxf(fmaf(t.x, a2s[cb + 4 * i + 0], c2s[cb + 4 * i + 0]), 0.f));
        lo[4 * i + 1] = f2bf(fmaxf(fmaf(t.y, a2s[cb + 4 * i + 1], c2s[cb + 4 * i + 1]), 0.f));
        lo[4 * i + 2] = f2bf(fmaxf(fmaf(t.z, a2s[cb + 4 * i + 2], c2s[cb + 4 * i + 2]), 0.f));
        lo[4 * i + 3] = f2bf(fmaxf(fmaf(t.w, a2s[cb + 4 * i + 3], c2s[cb + 4 * i + 3]), 0.f));
        hi[4 * i + 0] = f2bf(fmaxf(fmaf(u.x, a2s[cb + 8 + 4 * i + 0], c2s[cb + 8 + 4 * i + 0]), 0.f));
        hi[4 * i + 1] = f2bf(fmaxf(fmaf(u.y, a2s[cb + 8 + 4 * i + 1], c2s[cb + 8 + 4 * i + 1]), 0.f));
        hi[4 * i + 2] = f2bf(fmaxf(fmaf(u.z, a2s[cb + 8 + 4 * i + 2], c2s[cb + 8 + 4 * i + 2]), 0.f));
        hi[4 * i + 3] = f2bf(fmaxf(fmaf(u.w, a2s[cb + 8 + 4 * i + 3], c2s[cb + 8 + 4 * i + 3]), 0.f));
      }
      *(u16x8*)&H2[(size_t)grow * 64 + q * 16] = lo;
      *(u16x8*)&H2[(size_t)grow * 64 + q * 16 + 8] = hi;
    }
    char* base = (char*)At + r * 128;
    const int sw = (r & 7) << 4;
    *(u16x8*)(base + ((q * 32) ^ sw)) = lo;
    *(u16x8*)(base + ((q * 32 + 16) ^ sw)) = hi;
  }
  __syncthreads();
  const int l = tid & 63, w = tid >> 6;
  const int rowb = w * 16 + (l & 15);
  const char* abase = (const char*)At + rowb * 128;
  const int sw = (rowb & 7) << 4;
  const int kb = (l >> 4) << 4;
  const s16x8 a0 = *(const s16x8*)(abase + (kb ^ sw));
  const s16x8 a1 = *(const s16x8*)(abase + ((64 + kb) ^ sw));
  const u16x8* wp = (const u16x8*)WP3;
#pragma unroll 4
  for (int ct = 0; ct < 16; ++ct) {
    s16x8 b0 = (s16x8)wp[(ct * 2 + 0) * 64 + l];
    s16x8 b1 = (s16x8)wp[(ct * 2 + 1) * 64 + l];
    f32x4 acc = {0.f, 0.f, 0.f, 0.f};
    acc = mfma16(a0, b0, acc);
    acc = mfma16(a1, b1, acc);
    float sp = acc[0] + acc[1] + acc[2] + acc[3];
    float qp = acc[0] * acc[0] + acc[1] * acc[1] + acc[2] * acc[2] + acc[3] * acc[3];
    sp += __shfl_xor(sp, 16); sp += __shfl_xor(sp, 32);
    qp += __shfl_xor(qp, 16); qp += __shfl_xor(qp, 32);
    if ((l >> 4) == 0) {
      atomicAdd(&lsum[ct * 16 + (l & 15)], sp);
      atomicAdd(&lsq[ct * 16 + (l & 15)], qp);
    }
  }
  __syncthreads();
  for (int i = tid; i < 256; i += 256) {
    atomicAdd(&gsum[i], lsum[i]);
    atomicAdd(&gsq[i], lsq[i]);
  }
}

// ---- K5: out = relu(h2@W3s + X@Wss + cc) -----------------------------------
__global__ __launch_bounds__(256) void kFinal(const ushort* __restrict__ H2,
                                              const float* __restrict__ X,
                                              const ushort* __restrict__ WP3s,
                                              const ushort* __restrict__ WPSs,
                                              const float* __restrict__ ccv,
                                              float* __restrict__ OUT, int N) {
  __shared__ ushort Ah[64 * 64];
  __shared__ ushort Ax[64 * 64];
  const int tid = threadIdx.x;
  const int row0 = blockIdx.x * 64;
  {
    const int r = tid >> 2, q = tid & 3;
    const int grow = row0 + r;
    u16x8 lo = {0, 0, 0, 0, 0, 0, 0, 0}, hi = {0, 0, 0, 0, 0, 0, 0, 0};
    if (grow < N) {
      const u16x8* hp = (const u16x8*)&H2[(size_t)grow * 64 + q * 16];
      lo = hp[0];
      hi = hp[1];
    }
    char* base = (char*)Ah + r * 128;
    const int sw = (r & 7) << 4;
    *(u16x8*)(base + ((q * 32) ^ sw)) = lo;
    *(u16x8*)(base + ((q * 32 + 16) ^ sw)) = hi;
  }
  stageF32(Ax, X, row0, N, tid, 0.f);
  __syncthreads();
  const int l = tid & 63, w = tid >> 6;
  const int rowb = w * 16 + (l & 15);
  const int sw = (rowb & 7) << 4;
  const int kb = (l >> 4) << 4;
  const char* hb = (const char*)Ah + rowb * 128;
  const char* xb = (const char*)Ax + rowb * 128;
  const s16x8 ah0 = *(const s16x8*)(hb + (kb ^ sw));
  const s16x8 ah1 = *(const s16x8*)(hb + ((64 + kb) ^ sw));
  const s16x8 ax0 = *(const s16x8*)(xb + (kb ^ sw));
  const s16x8 ax1 = *(const s16x8*)(xb + ((64 + kb) ^ sw));
  const u16x8* wp3 = (const u16x8*)WP3s;
  const u16x8* wps = (const u16x8*)WPSs;
#pragma unroll 4
  for (int ct = 0; ct < 16; ++ct) {
    s16x8 b0 = (s16x8)wp3[(ct * 2 + 0) * 64 + l];
    s16x8 b1 = (s16x8)wp3[(ct * 2 + 1) * 64 + l];
    s16x8 s0 = (s16x8)wps[(ct * 2 + 0) * 64 + l];
    s16x8 s1 = (s16x8)wps[(ct * 2 + 1) * 64 + l];
    f32x4 acc = {0.f, 0.f, 0.f, 0.f};
    acc = mfma16(ah0, b0, acc);
    acc = mfma16(ah1, b1, acc);
    acc = mfma16(ax0, s0, acc);
    acc = mfma16(ax1, s1, acc);
    const int col = ct * 16 + (l & 15);
    const float cj = ccv[col];
#pragma unroll
    for (int reg = 0; reg < 4; ++reg) {
      const int grow = row0 + w * 16 + ((l >> 4) << 2) + reg;
      if (grow < N) OUT[(size_t)grow * 256 + col] = fmaxf(acc[reg] + cj, 0.f);
    }
  }
}

extern "C" void kernel_launch(void* const* d_in, const int* in_sizes, int n_in,
                              void* d_out, int out_size, void* d_ws, size_t ws_size,
                              hipStream_t stream) {
  const float* X  = (const float*)d_in[0];
  const int*   nbr = (const int*)d_in[1];
  const float* W1 = (const float*)d_in[2];
  const float* g1 = (const float*)d_in[3];
  const float* b1 = (const float*)d_in[4];
  const float* Wk = (const float*)d_in[5];
  const float* g2 = (const float*)d_in[6];
  const float* b2 = (const float*)d_in[7];
  const float* W3 = (const float*)d_in[8];
  const float* g3 = (const float*)d_in[9];
  const float* b3 = (const float*)d_in[10];
  const float* Ws = (const float*)d_in[11];
  const float* gs = (const float*)d_in[12];
  const float* bs = (const float*)d_in[13];
  float* out = (float*)d_out;
  float* ws  = (float*)d_ws;

  const int N = in_sizes[0] / 64;
  const float invN = 1.f / (float)N;

  // ws layout (float offsets)
  float* sum1S = ws + 0;     // [320] (0..63 = Y1, 64..319 = Ys)
  float* sq1S  = ws + 320;   // [320]
  float* sum2  = ws + 640;   // [64]
  float* sq2   = ws + 704;   // [64]
  float* sum3  = ws + 768;   // [256]
  float* sq3   = ws + 1024;  // [256]
  float* a1p = ws + 1280, *c1p = ws + 1344;
  float* aSp = ws + 1408, *cSp = ws + 1664;
  float* a2p = ws + 1920, *c2p = ws + 1984;
  float* a3p = ws + 2048, *c3p = ws + 2304;
  float* ccp = ws + 2560;                         // [256]
  ushort* WP1S = (ushort*)(ws + 2816);            // 20480 bf16
  ushort* WPkP = (ushort*)(ws + 13056);           // 36864 bf16
  ushort* WP3P = (ushort*)(ws + 31488);           // 16384 bf16
  ushort* WP3s = (ushort*)(ws + 39680);           // 16384 bf16
  ushort* WPSs = (ushort*)(ws + 47872);           // 16384 bf16
  ushort* H2b  = (ushort*)(ws + 56064);           // N*64 bf16 (~33 MB)
  // scratch in d_out (dead before kFinal writes)
  ushort* H1b = (ushort*)out;                     // N*64 bf16
  float*  Y2  = out + (size_t)N * 32;             // N*64 f32

  const int gb64 = (N + 63) / 64;

  kZero<<<5, 256, 0, stream>>>(ws, 1280);
  kPackW<<<288, 256, 0, stream>>>(W1, Ws, Wk, W3, WP1S, WPkP, WP3P);
  kStatsXW<<<gb64, 256, 0, stream>>>(X, WP1S, sum1S, sq1S, N);
  kFinStats<<<1, 64, 0, stream>>>(sum1S, sq1S, g1, b1, invN, a1p, c1p, 64);
  kFinStats<<<4, 64, 0, stream>>>(sum1S + 64, sq1S + 64, gs, bs, invN, aSp, cSp, 256);
  kGemm1<<<gb64, 256, 0, stream>>>(X, WP1S, a1p, c1p, H1b, N);
  kConv<<<gb64, 256, 0, stream>>>(H1b, nbr, WPkP, Y2, sum2, sq2, N);
  kFinStats<<<1, 64, 0, stream>>>(sum2, sq2, g2, b2, invN, a2p, c2p, 64);
  kH2S3<<<gb64, 256, 0, stream>>>(Y2, a2p, c2p, WP3P, H2b, sum3, sq3, N);
  kFinStats<<<4, 64, 0, stream>>>(sum3, sq3, g3, b3, invN, a3p, c3p, 256);
  kPackScaled<<<64, 256, 0, stream>>>(W3, Ws, a3p, aSp, c3p, cSp, WP3s, WPSs, ccp);
  kFinal<<<gb64, 256, 0, stream>>>(H2b, X, WP3s, WPSs, ccp, out, N);
}